// Round 3
// baseline (500.120 us; speedup 1.0000x reference)
//
#include <hip/hip_runtime.h>
#include <stdint.h>

typedef unsigned short u16;
typedef __attribute__((ext_vector_type(8))) short short8;
typedef __attribute__((ext_vector_type(4))) float f32x4;
typedef __attribute__((ext_vector_type(4))) unsigned short u16x4;

#define MFMA16(a, b, c) __builtin_amdgcn_mfma_f32_16x16x32_bf16((a), (b), (c), 0, 0, 0)

__device__ __forceinline__ float bf2f(u16 u) {
    union { uint32_t i; float f; } v;
    v.i = ((uint32_t)u) << 16;
    return v.f;
}
__device__ __forceinline__ u16 f2bf(float f) {  // round-to-nearest-even
    union { float f; uint32_t i; } v;
    v.f = f;
    uint32_t r = v.i + 0x7FFF + ((v.i >> 16) & 1);
    return (u16)(r >> 16);
}
// Bit-level Inf/NaN scrub — immune to fast-math folding.
__device__ __forceinline__ float scrub(float x) {
    union { float f; uint32_t i; } v;
    v.f = x;
    return ((v.i & 0x7F800000u) == 0x7F800000u) ? 0.f : x;
}

// ---------------------------------------------------------------------------
// Transpose 4 fp32 weight matrices (1024x1024) -> bf16 Wt[n][k] = W[k][n]
// ---------------------------------------------------------------------------
__global__ __launch_bounds__(256) void transpose4(
    const float* __restrict__ W0, const float* __restrict__ W1,
    const float* __restrict__ W2, const float* __restrict__ W3,
    u16* __restrict__ out)
{
    __shared__ u16 t[32][33];
    int z = blockIdx.z;
    const float* W = (z == 0) ? W0 : (z == 1) ? W1 : (z == 2) ? W2 : W3;
    u16* o = out + (size_t)z * 1048576;
    int tx = threadIdx.x & 31, ty = threadIdx.x >> 5;
    int x = blockIdx.x * 32 + tx;
    int yb = blockIdx.y * 32;
#pragma unroll
    for (int j = 0; j < 4; j++)
        t[ty + j * 8][tx] = f2bf(W[(size_t)(yb + ty + j * 8) * 1024 + x]);
    __syncthreads();
    int xo = yb + tx;
    int yob = blockIdx.x * 32;
#pragma unroll
    for (int j = 0; j < 4; j++)
        o[(size_t)(yob + ty + j * 8) * 1024 + xo] = t[tx][ty + j * 8];
}

// ---------------------------------------------------------------------------
// gemm_bt: C(M,N) = A(M,K)*Bt(N,K)^T + bias(N).  A fp32 (cvt->bf16 in
// staging), Bt bf16, K=1024.  128x128 tile, 4 waves.
// mode 0: bf16 out (b,h,l,d); 1: bf16 out (b,h,d,l); 3: fp32 out plain (m,n)
// ---------------------------------------------------------------------------
__global__ __launch_bounds__(256) void gemm_bt(
    const float* __restrict__ A, const u16* __restrict__ Bt,
    const float* __restrict__ bias, u16* __restrict__ outb,
    float* __restrict__ outf, int mode)
{
    __shared__ u16 As[128][40];
    __shared__ u16 Bs[128][40];
    const int K = 1024;
    int n0 = blockIdx.x * 128, m0 = blockIdx.y * 128;
    int tid = threadIdx.x;
    int w = tid >> 6, lane = tid & 63, g = lane >> 4, cc = lane & 15;
    int wm = (w >> 1) * 64, wn = (w & 1) * 64;
    int tr = tid >> 2, tc = (tid & 3) * 8;   // B staging: 64 rows x 32 cols
    int ar = tid >> 3, ac = (tid & 7) * 4;   // A staging: 32 rows x 32 cols (fp32)

    f32x4 acc[4][4];
#pragma unroll
    for (int i = 0; i < 4; i++)
#pragma unroll
        for (int j = 0; j < 4; j++) acc[i][j] = (f32x4){0.f, 0.f, 0.f, 0.f};

    for (int kb = 0; kb < K; kb += 32) {
        f32x4 av[4];
#pragma unroll
        for (int rr = 0; rr < 4; rr++)
            av[rr] = *(const f32x4*)&A[(size_t)(m0 + rr * 32 + ar) * K + kb + ac];
        short8 b0 = *(const short8*)&Bt[(size_t)(n0 + tr) * K + kb + tc];
        short8 b1 = *(const short8*)&Bt[(size_t)(n0 + 64 + tr) * K + kb + tc];
        __syncthreads();
#pragma unroll
        for (int rr = 0; rr < 4; rr++) {
            u16x4 ap;
#pragma unroll
            for (int r = 0; r < 4; r++) ap[r] = f2bf(av[rr][r]);
            *(u16x4*)&As[rr * 32 + ar][ac] = ap;
        }
        *(short8*)&Bs[tr][tc] = b0;
        *(short8*)&Bs[64 + tr][tc] = b1;
        __syncthreads();
        short8 af[4], bf[4];
#pragma unroll
        for (int mt = 0; mt < 4; mt++) af[mt] = *(const short8*)&As[wm + mt * 16 + cc][g * 8];
#pragma unroll
        for (int nt = 0; nt < 4; nt++) bf[nt] = *(const short8*)&Bs[wn + nt * 16 + cc][g * 8];
#pragma unroll
        for (int mt = 0; mt < 4; mt++)
#pragma unroll
            for (int nt = 0; nt < 4; nt++)
                acc[mt][nt] = MFMA16(af[mt], bf[nt], acc[mt][nt]);
    }

    // C-layout: row = g*4 + r, col = cc  (m89/m91-verified)
#pragma unroll
    for (int mt = 0; mt < 4; mt++) {
        int rl = wm + mt * 16 + g * 4;
#pragma unroll
        for (int nt = 0; nt < 4; nt++) {
            int n = n0 + wn + nt * 16 + cc;
            float bb = bias[n];
            if (mode == 1) {
                int m = m0 + rl;
                int b_ = m >> 10, l_ = m & 1023, h_ = n >> 6, d_ = n & 63;
                u16x4 pk;
#pragma unroll
                for (int r = 0; r < 4; r++) pk[r] = f2bf(scrub(acc[mt][nt][r] + bb));
                *(u16x4*)&outb[((size_t)(b_ * 16 + h_) * 64 + d_) * 1024 + l_] = pk;
            } else if (mode == 0) {
#pragma unroll
                for (int r = 0; r < 4; r++) {
                    int m = m0 + rl + r;
                    int b_ = m >> 10, l_ = m & 1023, h_ = n >> 6, d_ = n & 63;
                    outb[((size_t)(b_ * 16 + h_) * 1024 + l_) * 64 + d_] =
                        f2bf(scrub(acc[mt][nt][r] + bb));
                }
            } else {
#pragma unroll
                for (int r = 0; r < 4; r++) {
                    int m = m0 + rl + r;
                    outf[(size_t)m * 1024 + n] = scrub(acc[mt][nt][r] + bb);
                }
            }
        }
    }
}

// ---------------------------------------------------------------------------
// QE = qh_bh (1024x64 bf16) * e(1024x64 fp32->bf16)^T scattered into Srel
// (bf16) via the inverse of the reference skew (each cell written once):
//   B: Srel[qi][qi+mm-1023] = QEm[qi][mm]   (qi+mm >= 1023)
//   D: Srel[qi][qi+1]       = 0              (qi < 1023, via mm==1023 lane)
//   A: Srel[qi-1][mm+qi+1]  = QEm[qi][mm]   (qi>=1, mm+qi+1 <= 1023)
// where QEm = QE * (mm <= qi).
// ---------------------------------------------------------------------------
__global__ __launch_bounds__(256) void qe_srel(
    const u16* __restrict__ qh, const float* __restrict__ e, u16* __restrict__ Srel)
{
    __shared__ u16 As[128][40];
    __shared__ u16 Bs[128][40];
    int mb = blockIdx.x * 128;
    int qb = blockIdx.y * 128;
    int bh = blockIdx.z;
    const u16* A = qh + (size_t)bh * 65536;
    u16* S = Srel + (size_t)bh * 1048576;
    int tid = threadIdx.x;
    int w = tid >> 6, lane = tid & 63, g = lane >> 4, cc = lane & 15;
    int wm = (w >> 1) * 64, wn = (w & 1) * 64;
    int tr = tid >> 2, tc = (tid & 3) * 8;
    int ar = tid >> 3, ac = (tid & 7) * 4;

    f32x4 acc[4][4];
#pragma unroll
    for (int i = 0; i < 4; i++)
#pragma unroll
        for (int j = 0; j < 4; j++) acc[i][j] = (f32x4){0.f, 0.f, 0.f, 0.f};

    for (int kb = 0; kb < 64; kb += 32) {
        short8 a0 = *(const short8*)&A[(size_t)(qb + tr) * 64 + kb + tc];
        short8 a1 = *(const short8*)&A[(size_t)(qb + 64 + tr) * 64 + kb + tc];
        f32x4 bv[4];
#pragma unroll
        for (int rr = 0; rr < 4; rr++)
            bv[rr] = *(const f32x4*)&e[(size_t)(mb + rr * 32 + ar) * 64 + kb + ac];
        __syncthreads();
        *(short8*)&As[tr][tc] = a0;
        *(short8*)&As[64 + tr][tc] = a1;
#pragma unroll
        for (int rr = 0; rr < 4; rr++) {
            u16x4 bp;
#pragma unroll
            for (int r = 0; r < 4; r++) bp[r] = f2bf(bv[rr][r]);
            *(u16x4*)&Bs[rr * 32 + ar][ac] = bp;
        }
        __syncthreads();
        short8 af[4], bf[4];
#pragma unroll
        for (int mt = 0; mt < 4; mt++) af[mt] = *(const short8*)&As[wm + mt * 16 + cc][g * 8];
#pragma unroll
        for (int nt = 0; nt < 4; nt++) bf[nt] = *(const short8*)&Bs[wn + nt * 16 + cc][g * 8];
#pragma unroll
        for (int mt = 0; mt < 4; mt++)
#pragma unroll
            for (int nt = 0; nt < 4; nt++)
                acc[mt][nt] = MFMA16(af[mt], bf[nt], acc[mt][nt]);
    }

#pragma unroll
    for (int mt = 0; mt < 4; mt++)
#pragma unroll
        for (int nt = 0; nt < 4; nt++)
#pragma unroll
            for (int r = 0; r < 4; r++) {
                int qi = qb + wm + mt * 16 + g * 4 + r;
                int mm = mb + wn + nt * 16 + cc;
                u16 bv_ = (mm <= qi) ? f2bf(scrub(acc[mt][nt][r])) : (u16)0;
                int ki = qi + mm - 1023;
                if (ki >= 0) S[(size_t)qi * 1024 + ki] = bv_;
                if (mm == 1023 && qi < 1023) S[(size_t)qi * 1024 + qi + 1] = (u16)0;
                if (qi >= 1 && mm + qi + 1 <= 1023)
                    S[(size_t)(qi - 1) * 1024 + (mm + qi + 1)] = bv_;
            }
}

// ---------------------------------------------------------------------------
// Flash attention per (Q-tile 128, bh); 4 waves x 32 Q-rows each.
// S = qh*kh^T + Srel, /8, online softmax, O += P*V.  ctx out fp32.
// ---------------------------------------------------------------------------
__global__ __launch_bounds__(256) void flash(
    const u16* __restrict__ qh, const u16* __restrict__ kh,
    const u16* __restrict__ vht, const u16* __restrict__ Srel,
    float* __restrict__ ctx)
{
    __shared__ u16 Plds[4][32][136];
    int qt = blockIdx.x, bh = blockIdx.y;
    int w = threadIdx.x >> 6, lane = threadIdx.x & 63, g = lane >> 4, cc = lane & 15;
    const u16* Q = qh + (size_t)bh * 65536;
    const u16* Kp = kh + (size_t)bh * 65536;
    const u16* Vp = vht + (size_t)bh * 65536;
    const u16* S = Srel + (size_t)bh * 1048576;
    int q0 = qt * 128 + w * 32;

    short8 qf[2][2];
#pragma unroll
    for (int mt = 0; mt < 2; mt++)
#pragma unroll
        for (int ks = 0; ks < 2; ks++)
            qf[mt][ks] = *(const short8*)&Q[(size_t)(q0 + mt * 16 + cc) * 64 + ks * 32 + g * 8];

    float mi[2][4], li[2][4];
    f32x4 O[2][4];
#pragma unroll
    for (int mt = 0; mt < 2; mt++)
#pragma unroll
        for (int r = 0; r < 4; r++) { mi[mt][r] = -1e30f; li[mt][r] = 0.f; }
#pragma unroll
    for (int mt = 0; mt < 2; mt++)
#pragma unroll
        for (int d = 0; d < 4; d++) O[mt][d] = (f32x4){0.f, 0.f, 0.f, 0.f};

    const float LOG2E = 1.44269504088896f;

    for (int kt = 0; kt < 8; kt++) {
        int k0 = kt * 128;
        f32x4 sc[2][8];
#pragma unroll
        for (int mt = 0; mt < 2; mt++)
#pragma unroll
            for (int nt = 0; nt < 8; nt++) sc[mt][nt] = (f32x4){0.f, 0.f, 0.f, 0.f};

#pragma unroll
        for (int nt = 0; nt < 8; nt++) {
            short8 b0 = *(const short8*)&Kp[(size_t)(k0 + nt * 16 + cc) * 64 + g * 8];
            short8 b1 = *(const short8*)&Kp[(size_t)(k0 + nt * 16 + cc) * 64 + 32 + g * 8];
            sc[0][nt] = MFMA16(qf[0][0], b0, sc[0][nt]);
            sc[0][nt] = MFMA16(qf[0][1], b1, sc[0][nt]);
            sc[1][nt] = MFMA16(qf[1][0], b0, sc[1][nt]);
            sc[1][nt] = MFMA16(qf[1][1], b1, sc[1][nt]);
        }

#pragma unroll
        for (int mt = 0; mt < 2; mt++)
#pragma unroll
            for (int r = 0; r < 4; r++) {
                int row = q0 + mt * 16 + g * 4 + r;
                const u16* Srow = &S[(size_t)row * 1024 + k0];
#pragma unroll
                for (int nt = 0; nt < 8; nt++)
                    sc[mt][nt][r] = scrub((sc[mt][nt][r] + bf2f(Srow[nt * 16 + cc])) * 0.125f);
            }

#pragma unroll
        for (int mt = 0; mt < 2; mt++)
#pragma unroll
            for (int r = 0; r < 4; r++) {
                float mx = sc[mt][0][r];
#pragma unroll
                for (int nt = 1; nt < 8; nt++) mx = fmaxf(mx, sc[mt][nt][r]);
                mx = fmaxf(mx, __shfl_xor(mx, 1));
                mx = fmaxf(mx, __shfl_xor(mx, 2));
                mx = fmaxf(mx, __shfl_xor(mx, 4));
                mx = fmaxf(mx, __shfl_xor(mx, 8));
                float mnew = fmaxf(mi[mt][r], mx);
                float alpha = exp2f((mi[mt][r] - mnew) * LOG2E);
                mi[mt][r] = mnew;
                float rs = 0.f;
#pragma unroll
                for (int nt = 0; nt < 8; nt++) {
                    float p = exp2f((sc[mt][nt][r] - mnew) * LOG2E);
                    sc[mt][nt][r] = p;
                    rs += p;
                }
                rs += __shfl_xor(rs, 1);
                rs += __shfl_xor(rs, 2);
                rs += __shfl_xor(rs, 4);
                rs += __shfl_xor(rs, 8);
                li[mt][r] = li[mt][r] * alpha + rs;
#pragma unroll
                for (int d = 0; d < 4; d++) O[mt][d][r] *= alpha;
            }

#pragma unroll
        for (int mt = 0; mt < 2; mt++)
#pragma unroll
            for (int nt = 0; nt < 8; nt++)
#pragma unroll
                for (int r = 0; r < 4; r++)
                    Plds[w][mt * 16 + g * 4 + r][nt * 16 + cc] = f2bf(sc[mt][nt][r]);
        __syncthreads();

#pragma unroll
        for (int ks = 0; ks < 4; ks++) {
            short8 a0 = *(const short8*)&Plds[w][cc][ks * 32 + g * 8];
            short8 a1 = *(const short8*)&Plds[w][16 + cc][ks * 32 + g * 8];
#pragma unroll
            for (int d = 0; d < 4; d++) {
                short8 vb = *(const short8*)&Vp[(size_t)(d * 16 + cc) * 1024 + k0 + ks * 32 + g * 8];
                O[0][d] = MFMA16(a0, vb, O[0][d]);
                O[1][d] = MFMA16(a1, vb, O[1][d]);
            }
        }
        __syncthreads();
    }

    int b_ = bh >> 4, h_ = bh & 15;
#pragma unroll
    for (int mt = 0; mt < 2; mt++)
#pragma unroll
        for (int d = 0; d < 4; d++)
#pragma unroll
            for (int r = 0; r < 4; r++) {
                int l_ = q0 + mt * 16 + g * 4 + r;
                ctx[((size_t)b_ * 1024 + l_) * 1024 + h_ * 64 + d * 16 + cc] =
                    scrub(O[mt][d][r] / li[mt][r]);
            }
}

// ---------------------------------------------------------------------------
extern "C" void kernel_launch(void* const* d_in, const int* in_sizes, int n_in,
                              void* d_out, int out_size, void* d_ws, size_t ws_size,
                              hipStream_t stream)
{
    // Inputs are fp32 (reference dtype).  Identify by SIZE, robust to the
    // bool mask's representation: 4194304 -> k,v,q; 131072 -> E;
    // 1048576 -> Wk,Wv,Wq,Wo; 1024 -> bk,bv,bq,bo; others (mask) skipped.
    const float *k_in = nullptr, *v_in = nullptr, *q_in = nullptr, *E = nullptr;
    const float* W[4] = {nullptr, nullptr, nullptr, nullptr};
    const float* bs[4] = {nullptr, nullptr, nullptr, nullptr};
    int nqkv = 0, nW = 0, nb = 0;
    for (int i = 0; i < n_in; i++) {
        int s = in_sizes[i];
        const float* p = (const float*)d_in[i];
        if (s == 4194304) {
            if (nqkv == 0) k_in = p; else if (nqkv == 1) v_in = p; else if (nqkv == 2) q_in = p;
            nqkv++;
        } else if (s == 131072) {
            E = p;
        } else if (s == 1048576) {
            if (nW < 4) W[nW] = p;
            nW++;
        } else if (s == 1024) {
            if (nb < 4) bs[nb] = p;
            nb++;
        }
    }

    char* ws = (char*)d_ws;
    u16*   Wt   = (u16*)ws;                        // 8 MB  (4M bf16)
    u16*   khp  = (u16*)(ws + (8u << 20));         // 8 MB  (b,h,l,d)
    u16*   vhtp = (u16*)(ws + (16u << 20));        // 8 MB  (b,h,d,l)
    u16*   qhp  = (u16*)(ws + (24u << 20));        // 8 MB  (b,h,l,d)
    float* ctxp = (float*)(ws + (32u << 20));      // 16 MB (b,l,h*d) fp32
    u16*   Srel = (u16*)(ws + (48u << 20));        // 128 MB -> total 176 MB

    const size_t M1 = 1048576;
    transpose4<<<dim3(32, 32, 4), 256, 0, stream>>>(W[0], W[1], W[2], W[3], Wt);
    gemm_bt<<<dim3(8, 32), 256, 0, stream>>>(k_in, Wt + 0 * M1, bs[0], khp, nullptr, 0);
    gemm_bt<<<dim3(8, 32), 256, 0, stream>>>(v_in, Wt + 1 * M1, bs[1], vhtp, nullptr, 1);
    gemm_bt<<<dim3(8, 32), 256, 0, stream>>>(q_in, Wt + 2 * M1, bs[2], qhp, nullptr, 0);
    qe_srel<<<dim3(8, 8, 64), 256, 0, stream>>>(qhp, E + 1024 * 64, Srel);
    flash<<<dim3(8, 64), 256, 0, stream>>>(qhp, khp, vhtp, Srel, ctxp);
    gemm_bt<<<dim3(8, 32), 256, 0, stream>>>(ctxp, Wt + 3 * M1, bs[3], nullptr, (float*)d_out, 3);
}